// Round 10
// baseline (125.290 us; speedup 1.0000x reference)
//
#include <hip/hip_runtime.h>
#include <hip/hip_fp16.h>

// Problem constants
#define OOv   200
#define KKv   1600
#define OPAD  208             // 13 col-tiles of 16
#define NCHUNK 50             // K=32 chunks
#define CHUNK_BYTES 13312     // one K=32 chunk of W-fp16 (208*4 slots * 16B)
#define XSTR 40               // halfs per x row (80 B, mult of 16)
#define YSTR 56               // halfs per y row (112 B; 28-dw stride = 2-way banks, free)
#define ROWS 128              // rows per block

typedef _Float16 half8  __attribute__((ext_vector_type(8)));
typedef _Float16 half2v __attribute__((ext_vector_type(2)));
typedef __attribute__((ext_vector_type(4))) float floatx4;

// ---------------------------------------------------------------------------
// Pre-kernel: W [200][1600] fp32 -> Wh fp16, K-chunk-major, 16B-slot swizzled.
// idx = c*6656 + slot*8 + j ; slot = o*4 + (kg ^ ((o>>1)&3)) ; k = c*32+kg*8+j
// ---------------------------------------------------------------------------
__global__ void wb_convert_kernel(const float* __restrict__ W,
                                  unsigned short* __restrict__ Wh) {
    int idx = blockIdx.x * 256 + threadIdx.x;
    if (idx >= NCHUNK * OPAD * 32) return;     // 332800
    int j    = idx & 7;
    int slot = (idx >> 3) % (OPAD * 4);
    int c    = (idx >> 3) / (OPAD * 4);
    int o    = slot >> 2;
    int kgs  = slot & 3;
    int kg   = kgs ^ ((o >> 1) & 3);
    int k    = c * 32 + kg * 8 + j;
    float v  = (o < OOv) ? W[o * KKv + k] : 0.0f;
    union { _Float16 h; unsigned short u; } cv; cv.h = (_Float16)v;
    Wh[idx] = cv.u;
}

// ---------------------------------------------------------------------------
// One K=32 step, barrier-free, both operand streams register double-buffered.
// MF selects the intra-step ORDER (round-9 de-phasing experiment):
//   MF=false (waves 0-3): [W prefetch, y prefetch, af, MFMA]   (as round 9)
//   MF=true  (waves 4-7): [af, MFMA, W prefetch, y prefetch]
// Waves round-robin onto SIMDs (i%4), so each SIMD hosts one wave of each
// class; the classes' VALU/load phases now overlap the other class's MFMA
// phase instead of colliding with their own kind. Both orders are correct:
// prefetched data is consumed one full step (~1140 cyc) later either way.
// ---------------------------------------------------------------------------
template<int NT, int P, bool PREF, bool YPREF, bool MF>
__device__ __forceinline__ void gstep(
        const char* wg,                    // Wh + g*10*CHUNK_BYTES (uniform)
        int bfoff,
        const char* yb,                    // ylds + rowb*112 + kg*16
        half8 (&xq)[4],
        bool w1, bool w2, bool w3,
        half8 (&cur)[NT], half8 (&nxt)[NT],
        half8 (&yvc)[4], half8 (&yvn)[4],
        floatx4 (&acc)[4][4])
{
    constexpr int R32a[5] = {0, 64, 48, 32, 16};  // (32p mod 40) in bytes
    constexpr int B5a[5]  = {0, 0, 1, 2, 3};
    constexpr int WKa[5]  = {0, 1, 2, 3, 0};
    constexpr int pm = P % 5, pd = P / 5;
    constexpr int dbase = B5a[pm] + 4 * pd;
    constexpr int wk    = WKa[pm];
    const bool use = (wk == 1) ? w1 : (wk == 2) ? w2 : (wk == 3) ? w3 : false;

    // ---- prefetches BEFORE compute (class 0) ----
    if constexpr (!MF) {
        if constexpr (PREF) {
#pragma unroll
            for (int ct = 0; ct < NT; ++ct)
                nxt[ct] = *(const half8*)(wg + (size_t)(P + 1) * CHUNK_BYTES
                                          + bfoff + ct * 1024);
        }
        if constexpr (YPREF) {
            constexpr int pn    = (P + 1) % 5;
            constexpr int yimm2 = R32a[pn];
            constexpr int wk2   = WKa[pn];
            const bool use2 = (wk2 == 1) ? w1 : (wk2 == 2) ? w2
                            : (wk2 == 3) ? w3 : false;
            const char* ya2 = yb + (yimm2 - (use2 ? 80 : 0));
#pragma unroll
            for (int rt = 0; rt < 4; ++rt)
                yvn[rt] = *(const half8*)(ya2 + rt * 1792);
        }
    }

    // (b) A-fragments from REGISTER yvc: af[rt] = broadcast(x elem) * y window
    half8 af[4];
#pragma unroll
    for (int rt = 0; rt < 4; ++rt) {
        _Float16 e;
        if constexpr (wk == 0) {
            e = xq[rt][dbase];             // use==false at compile time
        } else {
            e = use ? xq[rt][dbase + 1] : xq[rt][dbase];
        }
        half8 xsp = {e, e, e, e, e, e, e, e};
        af[rt] = xsp * yvc[rt];
    }

    // (c) MFMA cluster on the previously prefetched W buffer
    __builtin_amdgcn_s_setprio(1);
#pragma unroll
    for (int ct = 0; ct < NT; ++ct)
#pragma unroll
        for (int rt = 0; rt < 4; ++rt)
            acc[rt][ct] = __builtin_amdgcn_mfma_f32_16x16x32_f16(
                af[rt], cur[ct], acc[rt][ct], 0, 0, 0);
    __builtin_amdgcn_s_setprio(0);

    // ---- prefetches AFTER compute (class 1) ----
    if constexpr (MF) {
        if constexpr (PREF) {
#pragma unroll
            for (int ct = 0; ct < NT; ++ct)
                nxt[ct] = *(const half8*)(wg + (size_t)(P + 1) * CHUNK_BYTES
                                          + bfoff + ct * 1024);
        }
        if constexpr (YPREF) {
            constexpr int pn    = (P + 1) % 5;
            constexpr int yimm2 = R32a[pn];
            constexpr int wk2   = WKa[pn];
            const bool use2 = (wk2 == 1) ? w1 : (wk2 == 2) ? w2
                            : (wk2 == 3) ? w3 : false;
            const char* ya2 = yb + (yimm2 - (use2 ? 80 : 0));
#pragma unroll
            for (int rt = 0; rt < 4; ++rt)
                yvn[rt] = *(const half8*)(ya2 + rt * 1792);
        }
    }
}

template<int NT, bool MF>
__device__ __forceinline__ void kloop(
        const char* wb, int bfoff,
        const char* yb, const char* xb,
        bool w1, bool w2, bool w3,
        floatx4 (&acc)[4][4])
{
    half8 bfA[NT], bfB[NT];
    half8 yvA[4], yvB[4];
    // preload chunk 0 into bfA; phase-0 y (yimm=0, use=false) into yvA
#pragma unroll
    for (int ct = 0; ct < NT; ++ct)
        bfA[ct] = *(const half8*)(wb + bfoff + ct * 1024);
#pragma unroll
    for (int rt = 0; rt < 4; ++rt)
        yvA[rt] = *(const half8*)(yb + rt * 1792);

#define GS(PP, PR, YP, CUR, NXT, YC, YN) \
    gstep<NT, PP, PR, YP, MF>(wg, bfoff, yb, xq, w1, w2, w3, CUR, NXT, YC, YN, acc)

#pragma unroll 1
    for (int g = 0; g < 4; ++g) {
        half8 xq[4];
#pragma unroll
        for (int rt = 0; rt < 4; ++rt)
            xq[rt] = *(const half8*)(xb + g * 16 + rt * 1280);
        const char* wg = wb + (size_t)g * 10 * CHUNK_BYTES;
        GS(0, true, true, bfA, bfB, yvA, yvB);
        GS(1, true, true, bfB, bfA, yvB, yvA);
        GS(2, true, true, bfA, bfB, yvA, yvB);
        GS(3, true, true, bfB, bfA, yvB, yvA);
        GS(4, true, true, bfA, bfB, yvA, yvB);
        GS(5, true, true, bfB, bfA, yvB, yvA);
        GS(6, true, true, bfA, bfB, yvA, yvB);
        GS(7, true, true, bfB, bfA, yvB, yvA);
        GS(8, true, true, bfA, bfB, yvA, yvB);
        GS(9, true, true, bfB, bfA, yvB, yvA);   // -> next group's bfA/yvA
    }
    // peeled group 4 (chunks 40..49): last step computes only
    {
        half8 xq[4];
#pragma unroll
        for (int rt = 0; rt < 4; ++rt)
            xq[rt] = *(const half8*)(xb + 4 * 16 + rt * 1280);
        const char* wg = wb + (size_t)4 * 10 * CHUNK_BYTES;
        GS(0, true, true, bfA, bfB, yvA, yvB);
        GS(1, true, true, bfB, bfA, yvB, yvA);
        GS(2, true, true, bfA, bfB, yvA, yvB);
        GS(3, true, true, bfB, bfA, yvB, yvA);
        GS(4, true, true, bfA, bfB, yvA, yvB);
        GS(5, true, true, bfB, bfA, yvB, yvA);
        GS(6, true, true, bfA, bfB, yvA, yvB);
        GS(7, true, true, bfB, bfA, yvB, yvA);
        GS(8, true, true, bfA, bfB, yvA, yvB);
        GS(9, false, false, bfB, bfA, yvB, yvA); // chunk 49: compute only
    }
#undef GS
}

// ---------------------------------------------------------------------------
// Main kernel: 512 blocks x 512 thr (8 waves), 128 rows x 208 cols per block.
// Waves: rowhalf = wave&1 (64 rows, rt=4), colgrp = wave>>1 in 0..3 owning
// 4/3/3/3 col-tiles (obase 0/64/112/160). acc[4][4] = 64 AGPR.
// __launch_bounds__(512,2): 256 regs/wave; 2 waves/SIMD. Round-9 experiment:
// waves 0-3 (one per SIMD under i%4 round-robin) use prefetch-first step
// order, waves 4-7 use MFMA-first, de-phasing the two waves on each SIMD so
// one's VALU/load phase overlaps the other's MFMA phase.
// W streamed from L1/L2 (Wh = 0.67 MB, L2-resident). K-loop: ZERO barriers.
// ---------------------------------------------------------------------------
__global__ __launch_bounds__(512, 2) void cin_mfma_kernel(
        const float* __restrict__ X, const float* __restrict__ Y,
        const unsigned short* __restrict__ Wh, float* __restrict__ Out) {
    __shared__ __align__(16) _Float16 xlds[ROWS * XSTR];           // 10240
    __shared__ __align__(16) _Float16 ylds[ROWS * YSTR];           // 14336

    const int tid     = threadIdx.x;
    const int wave    = tid >> 6;
    const int lane    = tid & 63;
    const int li      = lane & 15;
    const int kg      = lane >> 4;
    const int rowhalf = wave & 1;          // 64-row half
    const int colgrp  = wave >> 1;         // 0..3 -> 4/3/3/3 col-tiles
    const int ntiles  = colgrp ? 3 : 4;
    const int tbase   = colgrp ? (1 + colgrp * 3) : 0;   // 0,4,7,10
    const int obase   = tbase * 16;                      // 0,64,112,160
    const long blockbase = (long)blockIdx.x * ROWS;

    // ---- prologue: stage x,y (128 rows x 40) as fp16
    const float* xg = X + blockbase * 40;
    const float* yg = Y + blockbase * 40;
    for (int i = tid; i < 1280; i += 512) {
        int r  = i / 10;
        int c4 = (i % 10) * 4;                 // 40 % 4 == 0: row-aligned
        floatx4 vx = *(const floatx4*)(xg + i * 4);
        floatx4 vy = *(const floatx4*)(yg + i * 4);
        union { half2v h[2]; unsigned long long u; } px, py;
        px.h[0] = (half2v){(_Float16)vx.x, (_Float16)vx.y};
        px.h[1] = (half2v){(_Float16)vx.z, (_Float16)vx.w};
        py.h[0] = (half2v){(_Float16)vy.x, (_Float16)vy.y};
        py.h[1] = (half2v){(_Float16)vy.z, (_Float16)vy.w};
        *(unsigned long long*)(xlds + r * XSTR + c4) = px.u;
        *(unsigned long long*)(ylds + r * YSTR + c4) = py.u;
    }
    __syncthreads();    // the ONLY barrier

    floatx4 acc[4][4];
#pragma unroll
    for (int rt = 0; rt < 4; ++rt)
#pragma unroll
        for (int ct = 0; ct < 4; ++ct)
            acc[rt][ct] = (floatx4){0.f, 0.f, 0.f, 0.f};

    const int rowb = rowhalf * 64 + li;
    const char* yb = (const char*)ylds + rowb * (YSTR * 2) + kg * 16;
    const char* xb = (const char*)xlds + rowb * (XSTR * 2);
    const bool w1 = kg >= 1, w2 = kg >= 2, w3 = kg >= 3;

    // per-lane B-frag byte offset inside a global W chunk (16B-slot swizzle)
    const int bfoff = (obase + li) * 64 + ((kg ^ ((li >> 1) & 3)) * 16);

    const char* wb = (const char*)Wh;

    if (colgrp == 0)
        kloop<4, false>(wb, bfoff, yb, xb, w1, w2, w3, acc);
    else if (colgrp == 1)
        kloop<3, false>(wb, bfoff, yb, xb, w1, w2, w3, acc);
    else
        kloop<3, true>(wb, bfoff, yb, xb, w1, w2, w3, acc);

    // ---- epilogue: C/D layout col = lane&15, row = (lane>>4)*4 + reg  [m89]
#pragma unroll
    for (int rt = 0; rt < 4; ++rt) {
#pragma unroll
        for (int ct = 0; ct < 4; ++ct) {
            if (ct >= ntiles) continue;
            int gcol = obase + ct * 16 + li;
            if (gcol < OOv) {
#pragma unroll
                for (int r4 = 0; r4 < 4; ++r4) {
                    long grow = blockbase + rowhalf * 64 + rt * 16 + kg * 4 + r4;
                    Out[grow * OOv + gcol] = acc[rt][ct][r4];
                }
            }
        }
    }
}

extern "C" void kernel_launch(void* const* d_in, const int* in_sizes, int n_in,
                              void* d_out, int out_size, void* d_ws, size_t ws_size,
                              hipStream_t stream) {
    (void)in_sizes; (void)n_in; (void)out_size; (void)ws_size;
    const float* X = (const float*)d_in[0];
    const float* Y = (const float*)d_in[1];
    const float* W = (const float*)d_in[2];
    float* Out = (float*)d_out;
    unsigned short* Wh = (unsigned short*)d_ws;   // 665,600 B scratch

    wb_convert_kernel<<<1300, 256, 0, stream>>>(W, Wh);
    cin_mfma_kernel<<<512, 512, 0, stream>>>(X, Y, Wh, Out);
}

// Round 11
// 117.863 us; speedup vs baseline: 1.0630x; 1.0630x over previous
//
#include <hip/hip_runtime.h>
#include <hip/hip_fp16.h>

// Problem constants
#define OOv   200
#define KKv   1600
#define OPAD  208             // 13 col-tiles of 16
#define NCHUNK 50             // K=32 chunks
#define CHUNK_BYTES 13312     // one K=32 chunk of W-fp16 (208*4 slots * 16B)
#define XSTR 40               // halfs per x row (80 B, mult of 16)
#define YSTR 56               // halfs per y row (112 B; 28-dw stride = 2-way banks, free)
#define ROWS 128              // rows per block

typedef _Float16 half8  __attribute__((ext_vector_type(8)));
typedef _Float16 half2v __attribute__((ext_vector_type(2)));
typedef __attribute__((ext_vector_type(4))) float floatx4;

// ---------------------------------------------------------------------------
// Pre-kernel: W [200][1600] fp32 -> Wh fp16, K-chunk-major, 16B-slot swizzled.
// idx = c*6656 + slot*8 + j ; slot = o*4 + (kg ^ ((o>>1)&3)) ; k = c*32+kg*8+j
// ---------------------------------------------------------------------------
__global__ void wb_convert_kernel(const float* __restrict__ W,
                                  unsigned short* __restrict__ Wh) {
    int idx = blockIdx.x * 256 + threadIdx.x;
    if (idx >= NCHUNK * OPAD * 32) return;     // 332800
    int j    = idx & 7;
    int slot = (idx >> 3) % (OPAD * 4);
    int c    = (idx >> 3) / (OPAD * 4);
    int o    = slot >> 2;
    int kgs  = slot & 3;
    int kg   = kgs ^ ((o >> 1) & 3);
    int k    = c * 32 + kg * 8 + j;
    float v  = (o < OOv) ? W[o * KKv + k] : 0.0f;
    union { _Float16 h; unsigned short u; } cv; cv.h = (_Float16)v;
    Wh[idx] = cv.u;
}

// ---------------------------------------------------------------------------
// One K=32 step, barrier-free, W TRIPLE-buffered (2-step-ahead prefetch),
// y double-buffered. Round-10 lesson: collapsing the prefetch-to-use gap to
// ~80 cyc cost +11 us -> W-load latency exposure is first-order; under full
// 256-CU load, L2 queuing latency likely exceeds the ~580 cyc that 1-step
// prefetch covers. 2-step distance gives ~2280 cyc of cover.
//  (a)  issue chunk c+2's NT W-fragments into n2 (L1/L2-hot Wh)
//  (a2) prefetch step c+1's 4 y-fragments into yvn (compile-time offsets)
//  (b)  af build from REGISTER yvc (no lgkm wait)
//  (c)  MFMA cluster on cur (loaded 2 steps ago) under setprio(1)
// Cyclic WAR deps on the 3 buffers fence scheduler motion to ~1 step, so
// register pressure stays bounded (round-4 lesson).
// ---------------------------------------------------------------------------
template<int NT, int P, bool PREF, bool YPREF>
__device__ __forceinline__ void gstep(
        const char* wg,                    // Wh + g*10*CHUNK_BYTES (uniform)
        int bfoff,
        const char* yb,                    // ylds + rowb*112 + kg*16
        half8 (&xq)[4],
        bool w1, bool w2, bool w3,
        half8 (&cur)[NT], half8 (&n2)[NT],
        half8 (&yvc)[4], half8 (&yvn)[4],
        floatx4 (&acc)[4][4])
{
    constexpr int R32a[5] = {0, 64, 48, 32, 16};  // (32p mod 40) in bytes
    constexpr int B5a[5]  = {0, 0, 1, 2, 3};
    constexpr int WKa[5]  = {0, 1, 2, 3, 0};
    constexpr int pm = P % 5, pd = P / 5;
    constexpr int dbase = B5a[pm] + 4 * pd;
    constexpr int wk    = WKa[pm];
    const bool use = (wk == 1) ? w1 : (wk == 2) ? w2 : (wk == 3) ? w3 : false;

    // (a) W prefetch for step P+2 (contiguous chunks: P+2 past this group's
    //     10 simply lands in the next group's address range)
    if constexpr (PREF) {
#pragma unroll
        for (int ct = 0; ct < NT; ++ct)
            n2[ct] = *(const half8*)(wg + (size_t)(P + 2) * CHUNK_BYTES
                                     + bfoff + ct * 1024);
    }

    // (a2) y prefetch for step P+1 (phase depends on (P+1)%5 only)
    if constexpr (YPREF) {
        constexpr int pn    = (P + 1) % 5;
        constexpr int yimm2 = R32a[pn];
        constexpr int wk2   = WKa[pn];
        const bool use2 = (wk2 == 1) ? w1 : (wk2 == 2) ? w2
                        : (wk2 == 3) ? w3 : false;
        const char* ya2 = yb + (yimm2 - (use2 ? 80 : 0));   // >=0 by kg>=wk2
#pragma unroll
        for (int rt = 0; rt < 4; ++rt)
            yvn[rt] = *(const half8*)(ya2 + rt * 1792);     // 16 rows * 112 B
    }

    // (b) A-fragments from REGISTER yvc: af[rt] = broadcast(x elem) * y window
    half8 af[4];
#pragma unroll
    for (int rt = 0; rt < 4; ++rt) {
        _Float16 e;
        if constexpr (wk == 0) {
            e = xq[rt][dbase];             // use==false at compile time
        } else {
            e = use ? xq[rt][dbase + 1] : xq[rt][dbase];
        }
        half8 xsp = {e, e, e, e, e, e, e, e};
        af[rt] = xsp * yvc[rt];
    }

    // (c) MFMA cluster on the 2-steps-ago prefetched buffer
    __builtin_amdgcn_s_setprio(1);
#pragma unroll
    for (int ct = 0; ct < NT; ++ct)
#pragma unroll
        for (int rt = 0; rt < 4; ++rt)
            acc[rt][ct] = __builtin_amdgcn_mfma_f32_16x16x32_f16(
                af[rt], cur[ct], acc[rt][ct], 0, 0, 0);
    __builtin_amdgcn_s_setprio(0);
}

template<int NT>
__device__ __forceinline__ void kloop(
        const char* wb, int bfoff,
        const char* yb, const char* xb,
        bool w1, bool w2, bool w3,
        floatx4 (&acc)[4][4])
{
    half8 bfA[NT], bfB[NT], bfC[NT];
    half8 yvA[4], yvB[4];
    // preload chunk 0 -> bfA (consumed step 0); issue chunk 1 -> bfB
    // (consumed step 1); phase-0 y -> yvA.
#pragma unroll
    for (int ct = 0; ct < NT; ++ct)
        bfA[ct] = *(const half8*)(wb + bfoff + ct * 1024);
#pragma unroll
    for (int ct = 0; ct < NT; ++ct)
        bfB[ct] = *(const half8*)(wb + CHUNK_BYTES + bfoff + ct * 1024);
#pragma unroll
    for (int rt = 0; rt < 4; ++rt)
        yvA[rt] = *(const half8*)(yb + rt * 1792);

#define GS3(PP, PR, YP, CUR, NXT2, YC, YN) \
    gstep<NT, PP, PR, YP>(wg, bfoff, yb, xq, w1, w2, w3, CUR, NXT2, YC, YN, acc)

    // 10-step group: step i consumes buf[i%3], issues chunk (base+i+2) into
    // buf[(i+2)%3] (that buffer was consumed at step i-1, so it is free).
    // After 10 steps the rotation advances by 1 (10 mod 3).
#define GRP10(GIDX, BA, BB, BC, PR8, PR9, YP9)                                \
    {                                                                          \
        half8 xq[4];                                                           \
        _Pragma("unroll")                                                      \
        for (int rt = 0; rt < 4; ++rt)                                         \
            xq[rt] = *(const half8*)(xb + (GIDX) * 16 + rt * 1280);            \
        const char* wg = wb + (size_t)(GIDX) * 10 * CHUNK_BYTES;               \
        GS3(0, true, true,  BA, BC, yvA, yvB);                                 \
        GS3(1, true, true,  BB, BA, yvB, yvA);                                 \
        GS3(2, true, true,  BC, BB, yvA, yvB);                                 \
        GS3(3, true, true,  BA, BC, yvB, yvA);                                 \
        GS3(4, true, true,  BB, BA, yvA, yvB);                                 \
        GS3(5, true, true,  BC, BB, yvB, yvA);                                 \
        GS3(6, true, true,  BA, BC, yvA, yvB);                                 \
        GS3(7, true, true,  BB, BA, yvB, yvA);                                 \
        GS3(8, PR8,  true,  BC, BB, yvA, yvB);                                 \
        GS3(9, PR9,  YP9,   BA, BC, yvB, yvA);                                 \
    }

    GRP10(0, bfA, bfB, bfC, true,  true,  true)    // chunks  0..9
    GRP10(1, bfB, bfC, bfA, true,  true,  true)    // chunks 10..19
    GRP10(2, bfC, bfA, bfB, true,  true,  true)    // chunks 20..29
    GRP10(3, bfA, bfB, bfC, true,  true,  true)    // chunks 30..39
    GRP10(4, bfB, bfC, bfA, false, false, false)   // chunks 40..49 (tail)
#undef GRP10
#undef GS3
}

// ---------------------------------------------------------------------------
// Main kernel: 512 blocks x 512 thr (8 waves), 128 rows x 208 cols per block.
// Waves: rowhalf = wave&1 (64 rows, rt=4), colgrp = wave>>1 in 0..3 owning
// 4/3/3/3 col-tiles (obase 0/64/112/160). acc[4][4] = 64 AGPR.
// __launch_bounds__(512,2): 256 regs/wave; ~145 arch + 64 acc with triple-
// buffered W. 2 waves/SIMD, all prefetch-first (round-10's MFMA-first class
// reverted: it collapsed the prefetch distance and cost 11 us).
// W streamed from L1/L2 (Wh = 0.67 MB, L2-resident). K-loop: ZERO barriers.
// ---------------------------------------------------------------------------
__global__ __launch_bounds__(512, 2) void cin_mfma_kernel(
        const float* __restrict__ X, const float* __restrict__ Y,
        const unsigned short* __restrict__ Wh, float* __restrict__ Out) {
    __shared__ __align__(16) _Float16 xlds[ROWS * XSTR];           // 10240
    __shared__ __align__(16) _Float16 ylds[ROWS * YSTR];           // 14336

    const int tid     = threadIdx.x;
    const int wave    = tid >> 6;
    const int lane    = tid & 63;
    const int li      = lane & 15;
    const int kg      = lane >> 4;
    const int rowhalf = wave & 1;          // 64-row half
    const int colgrp  = wave >> 1;         // 0..3 -> 4/3/3/3 col-tiles
    const int ntiles  = colgrp ? 3 : 4;
    const int tbase   = colgrp ? (1 + colgrp * 3) : 0;   // 0,4,7,10
    const int obase   = tbase * 16;                      // 0,64,112,160
    const long blockbase = (long)blockIdx.x * ROWS;

    // ---- prologue: stage x,y (128 rows x 40) as fp16
    const float* xg = X + blockbase * 40;
    const float* yg = Y + blockbase * 40;
    for (int i = tid; i < 1280; i += 512) {
        int r  = i / 10;
        int c4 = (i % 10) * 4;                 // 40 % 4 == 0: row-aligned
        floatx4 vx = *(const floatx4*)(xg + i * 4);
        floatx4 vy = *(const floatx4*)(yg + i * 4);
        union { half2v h[2]; unsigned long long u; } px, py;
        px.h[0] = (half2v){(_Float16)vx.x, (_Float16)vx.y};
        px.h[1] = (half2v){(_Float16)vx.z, (_Float16)vx.w};
        py.h[0] = (half2v){(_Float16)vy.x, (_Float16)vy.y};
        py.h[1] = (half2v){(_Float16)vy.z, (_Float16)vy.w};
        *(unsigned long long*)(xlds + r * XSTR + c4) = px.u;
        *(unsigned long long*)(ylds + r * YSTR + c4) = py.u;
    }
    __syncthreads();    // the ONLY barrier

    floatx4 acc[4][4];
#pragma unroll
    for (int rt = 0; rt < 4; ++rt)
#pragma unroll
        for (int ct = 0; ct < 4; ++ct)
            acc[rt][ct] = (floatx4){0.f, 0.f, 0.f, 0.f};

    const int rowb = rowhalf * 64 + li;
    const char* yb = (const char*)ylds + rowb * (YSTR * 2) + kg * 16;
    const char* xb = (const char*)xlds + rowb * (XSTR * 2);
    const bool w1 = kg >= 1, w2 = kg >= 2, w3 = kg >= 3;

    // per-lane B-frag byte offset inside a global W chunk (16B-slot swizzle)
    const int bfoff = (obase + li) * 64 + ((kg ^ ((li >> 1) & 3)) * 16);

    const char* wb = (const char*)Wh;

    if (colgrp == 0)
        kloop<4>(wb, bfoff, yb, xb, w1, w2, w3, acc);
    else
        kloop<3>(wb, bfoff, yb, xb, w1, w2, w3, acc);

    // ---- epilogue: C/D layout col = lane&15, row = (lane>>4)*4 + reg  [m89]
#pragma unroll
    for (int rt = 0; rt < 4; ++rt) {
#pragma unroll
        for (int ct = 0; ct < 4; ++ct) {
            if (ct >= ntiles) continue;
            int gcol = obase + ct * 16 + li;
            if (gcol < OOv) {
#pragma unroll
                for (int r4 = 0; r4 < 4; ++r4) {
                    long grow = blockbase + rowhalf * 64 + rt * 16 + kg * 4 + r4;
                    Out[grow * OOv + gcol] = acc[rt][ct][r4];
                }
            }
        }
    }
}

extern "C" void kernel_launch(void* const* d_in, const int* in_sizes, int n_in,
                              void* d_out, int out_size, void* d_ws, size_t ws_size,
                              hipStream_t stream) {
    (void)in_sizes; (void)n_in; (void)out_size; (void)ws_size;
    const float* X = (const float*)d_in[0];
    const float* Y = (const float*)d_in[1];
    const float* W = (const float*)d_in[2];
    float* Out = (float*)d_out;
    unsigned short* Wh = (unsigned short*)d_ws;   // 665,600 B scratch

    wb_convert_kernel<<<1300, 256, 0, stream>>>(W, Wh);
    cin_mfma_kernel<<<512, 512, 0, stream>>>(X, Y, Wh, Out);
}

// Round 12
// 117.567 us; speedup vs baseline: 1.0657x; 1.0025x over previous
//
#include <hip/hip_runtime.h>
#include <hip/hip_fp16.h>

// Problem constants
#define OOv   200
#define KKv   1600
#define OPAD  208             // 13 col-tiles of 16
#define NCHUNK 50             // K=32 chunks
#define CHUNK_BYTES 13312     // one K=32 chunk of W-fp16 (208*4 slots * 16B)
#define XSTR 40               // halfs per x row (80 B, mult of 16)
#define YSTR 56               // halfs per y row (112 B; 28-dw stride = 2-way banks, free)
#define ROWS 128              // rows per block

typedef _Float16 half8  __attribute__((ext_vector_type(8)));
typedef _Float16 half2v __attribute__((ext_vector_type(2)));
typedef __attribute__((ext_vector_type(4))) float floatx4;

// ---------------------------------------------------------------------------
// Pre-kernel: W [200][1600] fp32 -> Wh fp16, K-chunk-major, 16B-slot swizzled.
// idx = c*6656 + slot*8 + j ; slot = o*4 + (kg ^ ((o>>1)&3)) ; k = c*32+kg*8+j
// ---------------------------------------------------------------------------
__global__ void wb_convert_kernel(const float* __restrict__ W,
                                  unsigned short* __restrict__ Wh) {
    int idx = blockIdx.x * 256 + threadIdx.x;
    if (idx >= NCHUNK * OPAD * 32) return;     // 332800
    int j    = idx & 7;
    int slot = (idx >> 3) % (OPAD * 4);
    int c    = (idx >> 3) / (OPAD * 4);
    int o    = slot >> 2;
    int kgs  = slot & 3;
    int kg   = kgs ^ ((o >> 1) & 3);
    int k    = c * 32 + kg * 8 + j;
    float v  = (o < OOv) ? W[o * KKv + k] : 0.0f;
    union { _Float16 h; unsigned short u; } cv; cv.h = (_Float16)v;
    Wh[idx] = cv.u;
}

// ---------------------------------------------------------------------------
// One K=32 step, barrier-free, REGISTER double-buffered (verified round-8
// optimum: 47.5 us, 883 TF effective ~ the m97-class structure ceiling).
//  (a) prefetch chunk c+1's NT fragments into nxt (L1/L2-hot Wh)
//  (b) af build (y ds_read + x broadcast-mul)
//  (c) MFMA cluster on cur (prefetched LAST step -> its L1/L2 latency hid
//      under the previous step's MFMA burst)
// Session ledger says this exact schedule is the optimum the compiler
// cooperates with: y-reg-dbuf = null; MFMA-first de-phasing = -11 us
// (collapsed prefetch distance); W triple-buffer = -30 us (allocator
// demotes buffers, 3.3M bank conflicts). Do not deviate.
// ---------------------------------------------------------------------------
template<int NT, int P, bool PREF>
__device__ __forceinline__ void gstep(
        const char* wg,                    // Wh + g*10*CHUNK_BYTES (uniform)
        int bfoff,
        const char* yb,                    // ylds + rowb*112 + kg*16
        half8 (&xq)[4],
        bool w1, bool w2, bool w3,
        half8 (&cur)[NT], half8 (&nxt)[NT],
        floatx4 (&acc)[4][4])
{
    constexpr int R32a[5] = {0, 64, 48, 32, 16};  // (32p mod 40) in bytes
    constexpr int B5a[5]  = {0, 0, 1, 2, 3};
    constexpr int WKa[5]  = {0, 1, 2, 3, 0};
    constexpr int pm = P % 5, pd = P / 5;
    constexpr int yimm  = R32a[pm];
    constexpr int dbase = B5a[pm] + 4 * pd;
    constexpr int wk    = WKa[pm];
    const bool use = (wk == 1) ? w1 : (wk == 2) ? w2 : (wk == 3) ? w3 : false;

    // (a) W prefetch for step P+1 (P=9 reads wg+10*CHUNK = next group's first)
    if constexpr (PREF) {
#pragma unroll
        for (int ct = 0; ct < NT; ++ct)
            nxt[ct] = *(const half8*)(wg + (size_t)(P + 1) * CHUNK_BYTES
                                      + bfoff + ct * 1024);
    }

    // (b) A-fragments: af[rt] = broadcast(x elem) * y window
    const char* ya = yb + (yimm - (use ? 80 : 0));   // >=0 by kg>=wk
    half8 af[4];
#pragma unroll
    for (int rt = 0; rt < 4; ++rt) {
        half8 yv = *(const half8*)(ya + rt * 1792);  // 16 rows * 112 B
        _Float16 e;
        if constexpr (wk == 0) {
            e = xq[rt][dbase];             // use==false at compile time
        } else {
            e = use ? xq[rt][dbase + 1] : xq[rt][dbase];
        }
        half8 xsp = {e, e, e, e, e, e, e, e};
        af[rt] = xsp * yv;
    }

    // (c) MFMA cluster on the previously prefetched buffer
    __builtin_amdgcn_s_setprio(1);
#pragma unroll
    for (int ct = 0; ct < NT; ++ct)
#pragma unroll
        for (int rt = 0; rt < 4; ++rt)
            acc[rt][ct] = __builtin_amdgcn_mfma_f32_16x16x32_f16(
                af[rt], cur[ct], acc[rt][ct], 0, 0, 0);
    __builtin_amdgcn_s_setprio(0);
}

template<int NT>
__device__ __forceinline__ void kloop(
        const char* wb, int bfoff,
        const char* yb, const char* xb,
        bool w1, bool w2, bool w3,
        floatx4 (&acc)[4][4])
{
    half8 bfA[NT], bfB[NT];
    // preload chunk 0 into bfA
#pragma unroll
    for (int ct = 0; ct < NT; ++ct)
        bfA[ct] = *(const half8*)(wb + bfoff + ct * 1024);

#define GS(PP, PR, CUR, NXT) \
    gstep<NT, PP, PR>(wg, bfoff, yb, xq, w1, w2, w3, CUR, NXT, acc)

#pragma unroll 1
    for (int g = 0; g < 4; ++g) {
        half8 xq[4];
#pragma unroll
        for (int rt = 0; rt < 4; ++rt)
            xq[rt] = *(const half8*)(xb + g * 16 + rt * 1280);
        const char* wg = wb + (size_t)g * 10 * CHUNK_BYTES;
        GS(0, true, bfA, bfB);
        GS(1, true, bfB, bfA);
        GS(2, true, bfA, bfB);
        GS(3, true, bfB, bfA);
        GS(4, true, bfA, bfB);
        GS(5, true, bfB, bfA);
        GS(6, true, bfA, bfB);
        GS(7, true, bfB, bfA);
        GS(8, true, bfA, bfB);
        GS(9, true, bfB, bfA);   // prefetches first chunk of group g+1 -> bfA
    }
    // peeled group 4 (chunks 40..49): last step computes only
    {
        half8 xq[4];
#pragma unroll
        for (int rt = 0; rt < 4; ++rt)
            xq[rt] = *(const half8*)(xb + 4 * 16 + rt * 1280);
        const char* wg = wb + (size_t)4 * 10 * CHUNK_BYTES;
        GS(0, true, bfA, bfB);
        GS(1, true, bfB, bfA);
        GS(2, true, bfA, bfB);
        GS(3, true, bfB, bfA);
        GS(4, true, bfA, bfB);
        GS(5, true, bfB, bfA);
        GS(6, true, bfA, bfB);
        GS(7, true, bfB, bfA);
        GS(8, true, bfA, bfB);
        GS(9, false, bfB, bfA);  // chunk 49: compute only
    }
#undef GS
}

// ---------------------------------------------------------------------------
// Main kernel: 512 blocks x 512 thr (8 waves), 128 rows x 208 cols per block.
// Waves: rowhalf = wave&1 (64 rows, rt=4), colgrp = wave>>1 in 0..3 owning
// 4/3/3/3 col-tiles (obase 0/64/112/160). acc[4][4] = 64 AGPR.
// __launch_bounds__(512,2): 256 regs/wave (round-7 lesson: arch demand is
// ~125-140; the 128-reg cap spilled 1.4 GB of scratch), 1 block/CU,
// 2 waves/SIMD; latency hiding via the per-wave register double buffer.
// W streamed from L1/L2 (Wh = 0.67 MB, L2-resident). K-loop: ZERO barriers.
// Verified: 47.5 us, 883 TF effective, ideal HBM traffic (70 MB), no spill.
// ---------------------------------------------------------------------------
__global__ __launch_bounds__(512, 2) void cin_mfma_kernel(
        const float* __restrict__ X, const float* __restrict__ Y,
        const unsigned short* __restrict__ Wh, float* __restrict__ Out) {
    __shared__ __align__(16) _Float16 xlds[ROWS * XSTR];           // 10240
    __shared__ __align__(16) _Float16 ylds[ROWS * YSTR];           // 14336

    const int tid     = threadIdx.x;
    const int wave    = tid >> 6;
    const int lane    = tid & 63;
    const int li      = lane & 15;
    const int kg      = lane >> 4;
    const int rowhalf = wave & 1;          // 64-row half
    const int colgrp  = wave >> 1;         // 0..3 -> 4/3/3/3 col-tiles
    const int ntiles  = colgrp ? 3 : 4;
    const int tbase   = colgrp ? (1 + colgrp * 3) : 0;   // 0,4,7,10
    const int obase   = tbase * 16;                      // 0,64,112,160
    const long blockbase = (long)blockIdx.x * ROWS;

    // ---- prologue: stage x,y (128 rows x 40) as fp16
    const float* xg = X + blockbase * 40;
    const float* yg = Y + blockbase * 40;
    for (int i = tid; i < 1280; i += 512) {
        int r  = i / 10;
        int c4 = (i % 10) * 4;                 // 40 % 4 == 0: row-aligned
        floatx4 vx = *(const floatx4*)(xg + i * 4);
        floatx4 vy = *(const floatx4*)(yg + i * 4);
        union { half2v h[2]; unsigned long long u; } px, py;
        px.h[0] = (half2v){(_Float16)vx.x, (_Float16)vx.y};
        px.h[1] = (half2v){(_Float16)vx.z, (_Float16)vx.w};
        py.h[0] = (half2v){(_Float16)vy.x, (_Float16)vy.y};
        py.h[1] = (half2v){(_Float16)vy.z, (_Float16)vy.w};
        *(unsigned long long*)(xlds + r * XSTR + c4) = px.u;
        *(unsigned long long*)(ylds + r * YSTR + c4) = py.u;
    }
    __syncthreads();    // the ONLY barrier

    floatx4 acc[4][4];
#pragma unroll
    for (int rt = 0; rt < 4; ++rt)
#pragma unroll
        for (int ct = 0; ct < 4; ++ct)
            acc[rt][ct] = (floatx4){0.f, 0.f, 0.f, 0.f};

    const int rowb = rowhalf * 64 + li;
    const char* yb = (const char*)ylds + rowb * (YSTR * 2) + kg * 16;
    const char* xb = (const char*)xlds + rowb * (XSTR * 2);
    const bool w1 = kg >= 1, w2 = kg >= 2, w3 = kg >= 3;

    // per-lane B-frag byte offset inside a global W chunk (16B-slot swizzle)
    const int bfoff = (obase + li) * 64 + ((kg ^ ((li >> 1) & 3)) * 16);

    const char* wb = (const char*)Wh;

    if (colgrp == 0)
        kloop<4>(wb, bfoff, yb, xb, w1, w2, w3, acc);
    else
        kloop<3>(wb, bfoff, yb, xb, w1, w2, w3, acc);

    // ---- epilogue: C/D layout col = lane&15, row = (lane>>4)*4 + reg  [m89]
#pragma unroll
    for (int rt = 0; rt < 4; ++rt) {
#pragma unroll
        for (int ct = 0; ct < 4; ++ct) {
            if (ct >= ntiles) continue;
            int gcol = obase + ct * 16 + li;
            if (gcol < OOv) {
#pragma unroll
                for (int r4 = 0; r4 < 4; ++r4) {
                    long grow = blockbase + rowhalf * 64 + rt * 16 + kg * 4 + r4;
                    Out[grow * OOv + gcol] = acc[rt][ct][r4];
                }
            }
        }
    }
}

extern "C" void kernel_launch(void* const* d_in, const int* in_sizes, int n_in,
                              void* d_out, int out_size, void* d_ws, size_t ws_size,
                              hipStream_t stream) {
    (void)in_sizes; (void)n_in; (void)out_size; (void)ws_size;
    const float* X = (const float*)d_in[0];
    const float* Y = (const float*)d_in[1];
    const float* W = (const float*)d_in[2];
    float* Out = (float*)d_out;
    unsigned short* Wh = (unsigned short*)d_ws;   // 665,600 B scratch

    wb_convert_kernel<<<1300, 256, 0, stream>>>(W, Wh);
    cin_mfma_kernel<<<512, 512, 0, stream>>>(X, Y, Wh, Out);
}